// Round 2
// baseline (104.391 us; speedup 1.0000x reference)
//
#include <hip/hip_runtime.h>
#include <math.h>

// Problem constants (from reference)
#define BS        1048576
#define N_AGENTS  8
#define N_HEAD    4
#define EMBED_DIM 64

// Output layout (flat f32, concatenated in return order):
//   [0,       BS*8)   head_attend == 0.5f everywhere (softmax over identical
//                     logits is uniform 1/8; summed over 4 heads -> 0.5)
//   [BS*8,    BS*9)   v == V[0] broadcast
//   [BS*9]            attend_mag_regs = 0.001 * sum_h dot(sel_w[h],key_w[h])^2
//   [BS*9+1, BS*9+5)  head_entropies = -log(0.125+1e-8) per head (constant)
//
// Fill region = 2359296 float4s. Each block owns a 1024-float4 chunk
// (256 threads x 4 iters, stride 256). Chunk 2048 is exactly the 0.5/V
// boundary (2097152 = 2048*1024), so the value choice is block-uniform.

#define NF4_HEAD  ((BS * N_AGENTS) / 4)        // 2097152
#define NF4_TOT   ((BS * (N_AGENTS + 1)) / 4)  // 2359296
#define CHUNK     1024                          // float4s per block
#define NBLOCKS   (NF4_TOT / CHUNK)             // 2304 (exact)
#define HEAD_BLKS (NF4_HEAD / CHUNK)            // 2048 (exact)

__global__ __launch_bounds__(256) void qatten_kernel(
    const float* __restrict__ sel_w,   // (4,64) flat = 256
    const float* __restrict__ key_w,   // (4,64) flat = 256
    const float* __restrict__ Vp,      // (1,)
    float* __restrict__ out)
{
    const int b = blockIdx.x;
    const int t = threadIdx.x;

    // Block-uniform value select: blocks [0,2048) write 0.5, [2048,2304) write V.
    const float val = (b < HEAD_BLKS) ? 0.5f : Vp[0];
    const float4 v4 = make_float4(val, val, val, val);

    float4* o4 = reinterpret_cast<float4*>(out) + (long long)b * CHUNK + t;
    #pragma unroll
    for (int k = 0; k < 4; ++k)
        o4[k * 256] = v4;

    // Block 0 additionally computes the two scalar tail outputs.
    if (b == 0) {
        float prod = sel_w[t] * key_w[t];          // one product per (head, dim)
        #pragma unroll
        for (int off = 32; off > 0; off >>= 1)     // wave-64 butterfly; head == wave
            prod += __shfl_down(prod, off, 64);

        __shared__ float dots[N_HEAD];
        if ((t & 63) == 0) dots[t >> 6] = prod;    // dot(sel_w[h], key_w[h])
        __syncthreads();

        if (t == 0) {
            float s = 0.0f;
            #pragma unroll
            for (int h = 0; h < N_HEAD; ++h) s += dots[h] * dots[h];
            out[(long long)BS * 9] = 0.001f * s;
        }
        if (t < N_HEAD) {
            const float p = 0.125f;                // probs are exactly 1/8
            out[(long long)BS * 9 + 1 + t] = -(8.0f * (p * logf(p + 1e-8f)));
        }
    }
}

extern "C" void kernel_launch(void* const* d_in, const int* in_sizes, int n_in,
                              void* d_out, int out_size, void* d_ws, size_t ws_size,
                              hipStream_t stream) {
    // inputs: 0=agent_qs (unused), 1=actions (unused), 2=sel_w, 3=key_w, 4=V
    const float* sel_w = (const float*)d_in[2];
    const float* key_w = (const float*)d_in[3];
    const float* Vp    = (const float*)d_in[4];
    float* out = (float*)d_out;

    qatten_kernel<<<NBLOCKS, 256, 0, stream>>>(sel_w, key_w, Vp, out);
}